// Round 2
// baseline (488.924 us; speedup 1.0000x reference)
//
#include <hip/hip_runtime.h>
#include <math.h>

#define T_TOK 8192
#define D_DIM 7168
#define E_EXP 256
#define TOPKN 8
#define NGRP 8
#define GSIZE 32
#define TOPG 4
#define ROUTE_SCALEF 2.5f

#define KSPLIT 4
#define KPER (D_DIM / KSPLIT)   // 1792
#define BM 128
#define BK 32                   // fp32 k-values per LDS tile
#define NTILE (KPER / BK)       // 56

typedef _Float16 f16;
typedef f16 f16x8 __attribute__((ext_vector_type(8)));
typedef f16 f16x4 __attribute__((ext_vector_type(4)));
typedef float f32x4 __attribute__((ext_vector_type(4)));

// ---------------- kernel 1: W fp32 -> f16 hi + (lo * 4096) ----------------
__global__ __launch_bounds__(256)
void split_w(const float* __restrict__ W, f16* __restrict__ Wh, f16* __restrict__ Wl) {
  int i = blockIdx.x * 256 + threadIdx.x;      // float4 index; grid covers exactly E*D/4
  float4 v = ((const float4*)W)[i];
  float pe[4] = {v.x, v.y, v.z, v.w};
  f16x4 h, l;
#pragma unroll
  for (int m = 0; m < 4; ++m) {
    f16 hh = (f16)pe[m];
    float rc = pe[m] - (float)hh;
    h[m] = hh;
    l[m] = (f16)(rc * 4096.0f);
  }
  ((f16x4*)Wh)[i] = h;
  ((f16x4*)Wl)[i] = l;
}

// ---------------- kernel 2: GEMM partial[ks] = X * W^T (split-f16 MFMA) ----------------
__device__ __forceinline__ void gload_lds16(const void* g, void* l) {
  __builtin_amdgcn_global_load_lds(
      (const __attribute__((address_space(1))) unsigned int*)g,
      (__attribute__((address_space(3))) unsigned int*)l, 16, 0, 0);
}

__global__ __launch_bounds__(512, 2)
void gate_gemm(const float* __restrict__ X, const f16* __restrict__ Wh,
               const f16* __restrict__ Wl, float* __restrict__ partial) {
  // LDS: 48 KB single-buffer. 64B rows -> bank-uniform b128 fragment reads.
  __shared__ f16 Ah[BM][BK], Al[BM][BK];
  __shared__ f16 Bh[E_EXP][BK], Bl[E_EXP][BK];

  const int tid  = threadIdx.x;
  const int lane = tid & 63;
  const int wid  = tid >> 6;              // 0..7
  const int mb   = blockIdx.x;            // 0..63
  const int ks   = blockIdx.y;            // 0..3
  const int kbase = ks * KPER;

  // A loader: thread -> row tid>>2 (0..127), k-seg (tid&3)*8
  const int ar = tid >> 2;
  const int ak = (tid & 3) * 8;
  const float* Xp = X + (size_t)(mb * BM + ar) * D_DIM + kbase + ak;

  // B loader: wave w stages 1KB chunks {2w,2w+1} of Bh and Bl (16 rows/chunk)
  const int bc0 = wid * 2;
  const int be  = lane >> 2;              // row within chunk
  const int bk  = (lane & 3) * 8;         // k-seg (16B)
  const f16* Whp = Wh + (size_t)(bc0 * 16 + be) * D_DIM + kbase + bk;
  const f16* Wlp = Wl + (size_t)(bc0 * 16 + be) * D_DIM + kbase + bk;

  // compute mapping: wave grid 2x4, wave-tile 64x64, 4x4 fragments of 16x16
  const int wm0 = (wid >> 2) * 64;
  const int wn0 = (wid & 3) * 64;
  const int fr  = lane & 15;
  const int fk  = (lane >> 4) * 8;

  f32x4 accA[4][4], accB[4][4];
#pragma unroll
  for (int i = 0; i < 4; ++i)
#pragma unroll
    for (int j = 0; j < 4; ++j) {
      accA[i][j] = f32x4{0.f, 0.f, 0.f, 0.f};
      accB[i][j] = f32x4{0.f, 0.f, 0.f, 0.f};
    }

  // prologue: A tile 0 in regs
  float4 pa0 = *(const float4*)(Xp);
  float4 pa1 = *(const float4*)(Xp + 4);

#pragma unroll 1
  for (int kt = 0; kt < NTILE; ++kt) {
    const int kc = kt * BK;

    // B: async global->LDS (pre-split f16, L2/L3-resident)
    gload_lds16(Whp + kc,                        &Bh[bc0 * 16][0]);
    gload_lds16(Whp + kc + (size_t)16 * D_DIM,   &Bh[(bc0 + 1) * 16][0]);
    gload_lds16(Wlp + kc,                        &Bl[bc0 * 16][0]);
    gload_lds16(Wlp + kc + (size_t)16 * D_DIM,   &Bl[(bc0 + 1) * 16][0]);

    // A: convert held regs, write LDS
    float pe[8] = {pa0.x, pa0.y, pa0.z, pa0.w, pa1.x, pa1.y, pa1.z, pa1.w};
    f16x8 hv, lv;
#pragma unroll
    for (int m = 0; m < 8; ++m) {
      f16 h = (f16)pe[m];
      float rc = pe[m] - (float)h;
      hv[m] = h;
      lv[m] = (f16)(rc * 4096.0f);
    }
    *(f16x8*)&Ah[ar][ak] = hv;
    *(f16x8*)&Al[ar][ak] = lv;

    // prefetch next A tile (latency hides under the barrier's vm drain)
    if (kt + 1 < NTILE) {
      pa0 = *(const float4*)(Xp + kc + BK);
      pa1 = *(const float4*)(Xp + kc + BK + 4);
    }

    __syncthreads();

    f16x8 b_h[4], b_l[4], a_h[4], a_l[4];
#pragma unroll
    for (int j = 0; j < 4; ++j) {
      b_h[j] = *(const f16x8*)&Bh[wn0 + j * 16 + fr][fk];
      b_l[j] = *(const f16x8*)&Bl[wn0 + j * 16 + fr][fk];
    }
#pragma unroll
    for (int i = 0; i < 4; ++i) {
      a_h[i] = *(const f16x8*)&Ah[wm0 + i * 16 + fr][fk];
      a_l[i] = *(const f16x8*)&Al[wm0 + i * 16 + fr][fk];
    }
#pragma unroll
    for (int i = 0; i < 4; ++i)
#pragma unroll
      for (int j = 0; j < 4; ++j) {
        accA[i][j] = __builtin_amdgcn_mfma_f32_16x16x32_f16(a_h[i], b_h[j], accA[i][j], 0, 0, 0);
        accB[i][j] = __builtin_amdgcn_mfma_f32_16x16x32_f16(a_h[i], b_l[j], accB[i][j], 0, 0, 0);
        accB[i][j] = __builtin_amdgcn_mfma_f32_16x16x32_f16(a_l[i], b_h[j], accB[i][j], 0, 0, 0);
      }

    __syncthreads();
  }

  // epilogue: dot = accA + accB * 2^-12 ; C/D layout col=lane&15, row=(lane>>4)*4+r
  const float s = 1.0f / 4096.0f;
  float* pout = partial + (size_t)ks * T_TOK * E_EXP;
#pragma unroll
  for (int i = 0; i < 4; ++i) {
    const int row0 = mb * BM + wm0 + i * 16 + (lane >> 4) * 4;
#pragma unroll
    for (int j = 0; j < 4; ++j) {
      const int col = wn0 + j * 16 + fr;
      f32x4 v = accA[i][j] + accB[i][j] * s;
#pragma unroll
      for (int r = 0; r < 4; ++r)
        pout[(size_t)(row0 + r) * E_EXP + col] = v[r];
    }
  }
}

// ---------------- kernel 3: reduce K-split partials + sigmoid ----------------
__global__ __launch_bounds__(256)
void reduce_sigmoid(const float* __restrict__ partial, float* __restrict__ scores) {
  const int g = blockIdx.x * 256 + threadIdx.x;   // float4 index over T*E/4
  const int Q = T_TOK * E_EXP / 4;                // 524288
  const float4* p = (const float4*)partial;
  float4 a = p[g], b = p[g + Q], c = p[g + 2 * Q], d = p[g + 3 * Q];
  float4 o;
  o.x = 1.f / (1.f + expf(-(a.x + b.x + c.x + d.x)));
  o.y = 1.f / (1.f + expf(-(a.y + b.y + c.y + d.y)));
  o.z = 1.f / (1.f + expf(-(a.z + b.z + c.z + d.z)));
  o.w = 1.f / (1.f + expf(-(a.w + b.w + c.w + d.w)));
  ((float4*)scores)[g] = o;
}

// ---------------- kernel 4: routing (top-2-per-group -> top-4 groups -> top-8) ----------------
// Tie semantics replicate jax.lax.top_k (descending value, lowest index first).
__global__ __launch_bounds__(256)
void gate_route(const float* __restrict__ scores, const float* __restrict__ bias,
                float* __restrict__ wout, float* __restrict__ iout, int T) {
  int t = blockIdx.x * blockDim.x + threadIdx.x;
  if (t >= T) return;
  const float* srow = scores + (size_t)t * E_EXP;

  float gs[NGRP];
#pragma unroll
  for (int g = 0; g < NGRP; ++g) {
    float m1 = -INFINITY, m2 = -INFINITY;
#pragma unroll 1
    for (int e = 0; e < GSIZE; ++e) {
      float v = srow[g * GSIZE + e] + bias[g * GSIZE + e];
      if (v > m1) { m2 = m1; m1 = v; }
      else if (v > m2) { m2 = v; }
    }
    gs[g] = m1 + m2;
  }

  int keepmask = 0;
#pragma unroll
  for (int r = 0; r < TOPG; ++r) {
    float bv = -INFINITY; int best = 0;
#pragma unroll
    for (int g = 0; g < NGRP; ++g) {
      bool used = (keepmask >> g) & 1;
      if (!used && gs[g] > bv) { bv = gs[g]; best = g; }
    }
    keepmask |= (1 << best);
  }

  float val[TOPKN]; int idx[TOPKN];
#pragma unroll
  for (int i = 0; i < TOPKN; ++i) { val[i] = -INFINITY; idx[i] = -1; }
#pragma unroll 1
  for (int g = 0; g < NGRP; ++g) {
    bool kept = (keepmask >> g) & 1;
#pragma unroll 1
    for (int e = 0; e < GSIZE; ++e) {
      int ex = g * GSIZE + e;
      float v = kept ? (srow[ex] + bias[ex]) : -INFINITY;
      if (v > val[TOPKN - 1]) {
        val[TOPKN - 1] = v; idx[TOPKN - 1] = ex;
#pragma unroll
        for (int p = TOPKN - 1; p > 0; --p) {
          if (val[p] > val[p - 1]) {
            float tv = val[p]; val[p] = val[p - 1]; val[p - 1] = tv;
            int   ti = idx[p]; idx[p] = idx[p - 1]; idx[p - 1] = ti;
          }
        }
      }
    }
  }

  float w[TOPKN]; float sum = 0.f;
#pragma unroll
  for (int i = 0; i < TOPKN; ++i) { w[i] = srow[idx[i]]; sum += w[i]; }
#pragma unroll
  for (int i = 0; i < TOPKN; ++i) {
    wout[(size_t)t * TOPKN + i] = (w[i] / sum) * ROUTE_SCALEF;
    iout[(size_t)t * TOPKN + i] = (float)idx[i];
  }
}

extern "C" void kernel_launch(void* const* d_in, const int* in_sizes, int n_in,
                              void* d_out, int out_size, void* d_ws, size_t ws_size,
                              hipStream_t stream) {
  const float* x  = (const float*)d_in[0];  // [T, D]
  const float* w  = (const float*)d_in[1];  // [E, D]
  const float* b  = (const float*)d_in[2];  // [E]
  float* out      = (float*)d_out;          // weights [T,8] then indices-as-float [T,8]

  // ws layout (~47 MB): Wh | Wl | partial[4][T][E] | scores[T][E]
  f16*   Wh      = (f16*)d_ws;
  f16*   Wl      = Wh + (size_t)E_EXP * D_DIM;
  float* partial = (float*)(Wl + (size_t)E_EXP * D_DIM);
  float* scores  = partial + (size_t)KSPLIT * T_TOK * E_EXP;

  split_w<<<E_EXP * D_DIM / 4 / 256, 256, 0, stream>>>(w, Wh, Wl);

  dim3 gg(T_TOK / BM, KSPLIT);   // (64, 4) = 256 blocks
  gate_gemm<<<gg, 512, 0, stream>>>(x, Wh, Wl, partial);

  reduce_sigmoid<<<T_TOK * E_EXP / 4 / 256, 256, 0, stream>>>(partial, scores);

  float* wout = out;
  float* iout = out + (size_t)T_TOK * TOPKN;
  gate_route<<<(T_TOK + 255) / 256, 256, 0, stream>>>(scores, b, wout, iout, T_TOK);
}

// Round 3
// 412.409 us; speedup vs baseline: 1.1855x; 1.1855x over previous
//
#include <hip/hip_runtime.h>
#include <math.h>

#define T_TOK 8192
#define D_DIM 7168
#define E_EXP 256
#define TOPKN 8
#define NGRP 8
#define TOPG 4
#define ROUTE_SCALEF 2.5f

#define BM 128
#define BK 32

typedef _Float16 f16;
typedef f16 f16x8 __attribute__((ext_vector_type(8)));
typedef float f32x4 __attribute__((ext_vector_type(4)));

// ---------------- kernel 1: W -> {64*hi, 64*lo} f16, pre-swizzled slot layout ----
// LDS read swizzle is slot^=(row>>1)&3; bake the same involution into the global
// image so global_load_lds (linear dest) + swizzled ds_read round-trips (rule 21).
__global__ __launch_bounds__(256)
void split_w(const float* __restrict__ W, f16* __restrict__ Wh, f16* __restrict__ Wl) {
  const int e  = blockIdx.x;
  const int se = (e >> 1) & 3;
  for (int s = threadIdx.x; s < D_DIM / 8; s += 256) {
    const int t = s >> 2, c = s & 3;
    const int kin  = t * 32 + ((c ^ se) << 3);
    const int kout = t * 32 + (c << 3);
    const float4 v0 = *(const float4*)(W + (size_t)e * D_DIM + kin);
    const float4 v1 = *(const float4*)(W + (size_t)e * D_DIM + kin + 4);
    const float pe[8] = {v0.x, v0.y, v0.z, v0.w, v1.x, v1.y, v1.z, v1.w};
    f16x8 h, l;
#pragma unroll
    for (int m = 0; m < 8; ++m) {
      const float hf = (float)(f16)pe[m];
      h[m] = (f16)(hf * 64.0f);              // exact exponent shift
      l[m] = (f16)((pe[m] - hf) * 64.0f);
    }
    *(f16x8*)(Wh + (size_t)e * D_DIM + kout) = h;
    *(f16x8*)(Wl + (size_t)e * D_DIM + kout) = l;
  }
}

// ---------------- kernel 2: partial[ks] = (64X)*(64W)^T via 3-chain f16 MFMA ----
__device__ __forceinline__ void gload_lds16(const void* g, void* l) {
  __builtin_amdgcn_global_load_lds(
      (const __attribute__((address_space(1))) unsigned int*)g,
      (__attribute__((address_space(3))) unsigned int*)l, 16, 0, 0);
}

__global__ __launch_bounds__(512, 4)
void gate_gemm(const float* __restrict__ X, const f16* __restrict__ Wh,
               const f16* __restrict__ Wl, float* __restrict__ partial, int kper) {
  __shared__ f16 Ah[BM][BK], Al[BM][BK];
  __shared__ f16 Bh[E_EXP][BK], Bl[E_EXP][BK];

  const int tid   = threadIdx.x;
  const int lane  = tid & 63;
  const int wid   = tid >> 6;            // 0..7
  const int mb    = blockIdx.x;
  const int ks    = blockIdx.y;
  const int kbase = ks * kper;
  const int ntile = kper >> 5;

  // A loader: row = wid*16 + (lane&15), slot = lane>>4  (matches read footprint)
  const int sr = wid * 16 + (lane & 15);
  const int sc = lane >> 4;
  const float* Xp = X + (size_t)(mb * BM + sr) * D_DIM + kbase + (sc << 3);
  const int awoff = ((sc ^ ((sr >> 1) & 3)) << 3);   // swizzled f16 offset in row

  // B loader: wave stages rows [32w,32w+32) of Bh and Bl (global pre-swizzled)
  const f16* Whp = Wh + (size_t)(wid * 32 + (lane >> 2)) * D_DIM + kbase + ((lane & 3) << 3);
  const f16* Wlp = Wl + (size_t)(wid * 32 + (lane >> 2)) * D_DIM + kbase + ((lane & 3) << 3);

  // compute mapping: 2x4 wave grid, 64x64 wave-tile, 4x4 frags of 16x16x32
  const int wm0 = (wid >> 2) * 64;
  const int wn0 = (wid & 3) * 64;
  const int fr  = lane & 15;
  const int rdoff = (((lane >> 4) << 3)) ^ (((fr >> 1) & 3) << 3);  // fk ^ swz(row)

  f32x4 acc[4][4];
#pragma unroll
  for (int i = 0; i < 4; ++i)
#pragma unroll
    for (int j = 0; j < 4; ++j) acc[i][j] = f32x4{0.f, 0.f, 0.f, 0.f};

  float4 pa0 = *(const float4*)(Xp);
  float4 pa1 = *(const float4*)(Xp + 4);

#pragma unroll 1
  for (int kt = 0; kt < ntile; ++kt) {
    const int kc = kt << 5;

    // B: async global->LDS (linear dest; swizzle pre-baked in source layout)
    gload_lds16(Whp + kc,                      &Bh[wid * 32][0]);
    gload_lds16(Whp + kc + (size_t)16 * D_DIM, &Bh[wid * 32 + 16][0]);
    gload_lds16(Wlp + kc,                      &Bl[wid * 32][0]);
    gload_lds16(Wlp + kc + (size_t)16 * D_DIM, &Bl[wid * 32 + 16][0]);

    // prefetch next A chunk first (hide HBM latency under convert+barrier)
    const int knext = (kt + 1 < ntile) ? kc + 32 : kc;
    const float4 na0 = *(const float4*)(Xp + knext);
    const float4 na1 = *(const float4*)(Xp + knext + 4);

    // convert current A regs -> swizzled LDS
    const float pe[8] = {pa0.x, pa0.y, pa0.z, pa0.w, pa1.x, pa1.y, pa1.z, pa1.w};
    f16x8 hv, lv;
#pragma unroll
    for (int m = 0; m < 8; ++m) {
      const float hf = (float)(f16)pe[m];
      hv[m] = (f16)(hf * 64.0f);
      lv[m] = (f16)((pe[m] - hf) * 64.0f);
    }
    *(f16x8*)&Ah[sr][awoff] = hv;
    *(f16x8*)&Al[sr][awoff] = lv;
    pa0 = na0; pa1 = na1;

    __syncthreads();

    f16x8 bh0 = *(const f16x8*)&Bh[wn0 +  0 + fr][rdoff];
    f16x8 bl0 = *(const f16x8*)&Bl[wn0 +  0 + fr][rdoff];
    f16x8 bh1 = *(const f16x8*)&Bh[wn0 + 16 + fr][rdoff];
    f16x8 bl1 = *(const f16x8*)&Bl[wn0 + 16 + fr][rdoff];
    f16x8 bh2 = *(const f16x8*)&Bh[wn0 + 32 + fr][rdoff];
    f16x8 bl2 = *(const f16x8*)&Bl[wn0 + 32 + fr][rdoff];
    f16x8 bh3 = *(const f16x8*)&Bh[wn0 + 48 + fr][rdoff];
    f16x8 bl3 = *(const f16x8*)&Bl[wn0 + 48 + fr][rdoff];
#pragma unroll
    for (int i = 0; i < 4; ++i) {
      const f16x8 ah = *(const f16x8*)&Ah[wm0 + i * 16 + fr][rdoff];
      const f16x8 al = *(const f16x8*)&Al[wm0 + i * 16 + fr][rdoff];
      acc[i][0] = __builtin_amdgcn_mfma_f32_16x16x32_f16(ah, bh0, acc[i][0], 0, 0, 0);
      acc[i][0] = __builtin_amdgcn_mfma_f32_16x16x32_f16(ah, bl0, acc[i][0], 0, 0, 0);
      acc[i][0] = __builtin_amdgcn_mfma_f32_16x16x32_f16(al, bh0, acc[i][0], 0, 0, 0);
      acc[i][1] = __builtin_amdgcn_mfma_f32_16x16x32_f16(ah, bh1, acc[i][1], 0, 0, 0);
      acc[i][1] = __builtin_amdgcn_mfma_f32_16x16x32_f16(ah, bl1, acc[i][1], 0, 0, 0);
      acc[i][1] = __builtin_amdgcn_mfma_f32_16x16x32_f16(al, bh1, acc[i][1], 0, 0, 0);
      acc[i][2] = __builtin_amdgcn_mfma_f32_16x16x32_f16(ah, bh2, acc[i][2], 0, 0, 0);
      acc[i][2] = __builtin_amdgcn_mfma_f32_16x16x32_f16(ah, bl2, acc[i][2], 0, 0, 0);
      acc[i][2] = __builtin_amdgcn_mfma_f32_16x16x32_f16(al, bh2, acc[i][2], 0, 0, 0);
      acc[i][3] = __builtin_amdgcn_mfma_f32_16x16x32_f16(ah, bh3, acc[i][3], 0, 0, 0);
      acc[i][3] = __builtin_amdgcn_mfma_f32_16x16x32_f16(ah, bl3, acc[i][3], 0, 0, 0);
      acc[i][3] = __builtin_amdgcn_mfma_f32_16x16x32_f16(al, bh3, acc[i][3], 0, 0, 0);
    }
    __syncthreads();
  }

  // epilogue: unscale (operands were each *64 -> acc *4096)
  const float s = 1.0f / 4096.0f;
  float* pout = partial + (size_t)ks * T_TOK * E_EXP;
#pragma unroll
  for (int i = 0; i < 4; ++i) {
    const int row0 = mb * BM + wm0 + i * 16 + (lane >> 4) * 4;
#pragma unroll
    for (int j = 0; j < 4; ++j) {
      const int col = wn0 + j * 16 + fr;
      const f32x4 v = acc[i][j] * s;
#pragma unroll
      for (int r = 0; r < 4; ++r)
        pout[(size_t)(row0 + r) * E_EXP + col] = v[r];
    }
  }
}

// ---------------- kernel 3: fused reduce + sigmoid + routing, one wave/token ----
__global__ __launch_bounds__(256)
void gate_route(const float* __restrict__ partial, const float* __restrict__ bias,
                float* __restrict__ wout, float* __restrict__ iout, int ksplit) {
  const int t    = (blockIdx.x * 256 + threadIdx.x) >> 6;
  const int lane = threadIdx.x & 63;

  // reduce K-split partials: lane owns experts 4*lane .. 4*lane+3
  float sx = 0.f, sy = 0.f, sz = 0.f, sw = 0.f;
  for (int ks = 0; ks < ksplit; ++ks) {
    const float4 p = *(const float4*)(partial + ((size_t)ks * T_TOK + t) * E_EXP + (lane << 2));
    sx += p.x; sy += p.y; sz += p.z; sw += p.w;
  }
  const float o0 = 1.f / (1.f + expf(-sx));
  const float o1 = 1.f / (1.f + expf(-sy));
  const float o2 = 1.f / (1.f + expf(-sz));
  const float o3 = 1.f / (1.f + expf(-sw));
  const float4 bv4 = *(const float4*)(bias + (lane << 2));
  const float b0 = o0 + bv4.x, b1 = o1 + bv4.y, b2 = o2 + bv4.z, b3 = o3 + bv4.w;

  // top-2 within lane (values only; ties irrelevant for the sum)
  const float ma = fmaxf(b0, b1), mi = fminf(b0, b1);
  const float mb_ = fmaxf(b2, b3), mn = fminf(b2, b3);
  float m1 = fmaxf(ma, mb_);
  float m2 = fmaxf(fminf(ma, mb_), fmaxf(mi, mn));
  // merge across the 8 lanes of this group (lanes l^1, l^2, l^4 same group)
#pragma unroll
  for (int msk = 1; msk <= 4; msk <<= 1) {
    const float p1 = __shfl_xor(m1, msk);
    const float p2 = __shfl_xor(m2, msk);
    const float nm1 = fmaxf(m1, p1);
    const float nm2 = fmaxf(fminf(m1, p1), fmaxf(m2, p2));
    m1 = nm1; m2 = nm2;
  }
  const float gs = m1 + m2;

  // all 8 group scores everywhere, then serial top-4 (ties -> lowest group idx)
  float ga[8];
#pragma unroll
  for (int g = 0; g < 8; ++g) ga[g] = __shfl(gs, g * 8);
  int keepmask = 0;
#pragma unroll
  for (int r = 0; r < TOPG; ++r) {
    float bvv = -INFINITY; int bg = 0;
#pragma unroll
    for (int g = 0; g < NGRP; ++g) {
      const bool better = !((keepmask >> g) & 1) && (ga[g] > bvv);
      bvv = better ? ga[g] : bvv;
      bg  = better ? g : bg;
    }
    keepmask |= 1 << bg;
  }

  const bool kept = (keepmask >> (lane >> 3)) & 1;
  const float c0 = kept ? b0 : -INFINITY;
  const float c1 = kept ? b1 : -INFINITY;
  const float c2 = kept ? b2 : -INFINITY;
  const float c3 = kept ? b3 : -INFINITY;

  // 8 rounds of wave-wide argmax (max value, ties -> min expert index)
  int used = 0;
  float sum = 0.f, selw = 0.f;
  int seli = 0;
#pragma unroll
  for (int r = 0; r < TOPKN; ++r) {
    float bv_ = -INFINITY; int bi_ = 0x7FFFFFFF; float bo_ = 0.f;
    { const bool ok = !(used & 1) && (c0 > bv_); bv_ = ok ? c0 : bv_; bi_ = ok ? (lane << 2)     : bi_; bo_ = ok ? o0 : bo_; }
    { const bool ok = !(used & 2) && (c1 > bv_); bv_ = ok ? c1 : bv_; bi_ = ok ? (lane << 2) | 1 : bi_; bo_ = ok ? o1 : bo_; }
    { const bool ok = !(used & 4) && (c2 > bv_); bv_ = ok ? c2 : bv_; bi_ = ok ? (lane << 2) | 2 : bi_; bo_ = ok ? o2 : bo_; }
    { const bool ok = !(used & 8) && (c3 > bv_); bv_ = ok ? c3 : bv_; bi_ = ok ? (lane << 2) | 3 : bi_; bo_ = ok ? o3 : bo_; }
#pragma unroll
    for (int m = 1; m < 64; m <<= 1) {
      const float vp = __shfl_xor(bv_, m);
      const int   ip = __shfl_xor(bi_, m);
      const float op = __shfl_xor(bo_, m);
      const bool take = (vp > bv_) || (vp == bv_ && ip < bi_);
      bv_ = take ? vp : bv_; bi_ = take ? ip : bi_; bo_ = take ? op : bo_;
    }
    sum += bo_;
    if (lane == r) { selw = bo_; seli = bi_; }
    if ((bi_ >> 2) == lane) used |= 1 << (bi_ & 3);
  }

  if (lane < TOPKN) {
    wout[(size_t)t * TOPKN + lane] = (selw / sum) * ROUTE_SCALEF;
    iout[(size_t)t * TOPKN + lane] = (float)seli;
  }
}

extern "C" void kernel_launch(void* const* d_in, const int* in_sizes, int n_in,
                              void* d_out, int out_size, void* d_ws, size_t ws_size,
                              hipStream_t stream) {
  const float* x = (const float*)d_in[0];
  const float* w = (const float*)d_in[1];
  const float* b = (const float*)d_in[2];
  float* out = (float*)d_out;

  const size_t whl = (size_t)E_EXP * D_DIM * sizeof(f16);          // 3.67 MB each
  const size_t per_split = (size_t)T_TOK * E_EXP * sizeof(float);  // 8.39 MB
  const int ksplit = (ws_size >= 2 * whl + 8 * per_split) ? 8 : 4; // deterministic

  f16* Wh = (f16*)d_ws;
  f16* Wl = Wh + (size_t)E_EXP * D_DIM;
  float* partial = (float*)(Wl + (size_t)E_EXP * D_DIM);

  split_w<<<E_EXP, 256, 0, stream>>>(w, Wh, Wl);

  dim3 gg(T_TOK / BM, ksplit);
  gate_gemm<<<gg, 512, 0, stream>>>(x, Wh, Wl, partial, D_DIM / ksplit);

  float* wout = out;
  float* iout = out + (size_t)T_TOK * TOPKN;
  gate_route<<<T_TOK / 4, 256, 0, stream>>>(partial, b, wout, iout, ksplit);
}